// Round 17
// baseline (69.229 us; speedup 1.0000x reference)
//
#include <hip/hip_runtime.h>
#include <hip/hip_fp16.h>
#include <math.h>

typedef _Float16 f16x8 __attribute__((ext_vector_type(8)));
typedef float f32x4 __attribute__((ext_vector_type(4)));

#define NS 4
#define HID 512
#define IN_DIM 342
#define OUT_DIM 311
#define BATCH 1024
#define INP 352            // IN_DIM padded to mult of 32
#define K0V (NS*INP)       // 1408
#define K12V (NS*HID)      // 2048
#define XROW (IN_DIM+1)    // 343

// workspace float offsets (~11.9 MB)
#define OFF_ACOEF 0
#define OFF_X0H   4096
#define OFF_W0H   (OFF_X0H + 720896)
#define OFF_W1H   (OFF_W0H + 360448)
#define OFF_W2H   (OFF_W1H + 524288)
#define OFF_H1X   (OFF_W2H + 327680)
#define OFF_H2X   OFF_X0H      // overlays X0h+part of W0h (dead after L0)

typedef __attribute__((address_space(3))) void lds_t;
typedef __attribute__((address_space(1))) const void gvm_t;
__device__ __forceinline__ void gload16(const void* g, void* l) {
    __builtin_amdgcn_global_load_lds((gvm_t*)g, (lds_t*)l, 16, 0, 0);
}

// ---- fused prep kernel (R4/R12-proven, unchanged) ----
__global__ __launch_bounds__(256) void prep_all(
    const float* __restrict__ x,
    const float* __restrict__ W0, const float* __restrict__ W1,
    const float* __restrict__ W2,
    float* __restrict__ acoef,
    __half* __restrict__ X0h, __half* __restrict__ W0h,
    __half* __restrict__ W1h, __half* __restrict__ W2h)
{
    const int bid = blockIdx.x;
    const int t = threadIdx.x;
    if (bid < 512) {                       // W0h
        int o = bid;
        for (int k = t; k < K0V; k += 256) {
            int s = k / INP;
            int i = k - s*INP;
            float v = 0.f;
            if (i < IN_DIM) v = W0[((size_t)s*HID + o)*IN_DIM + i];
            W0h[(size_t)o*K0V + k] = __float2half(v);
        }
    } else if (bid < 1024) {               // W1h
        int o = bid - 512;
        int k = t * 8;
        int s = k >> 9, i = k & 511;
        const float* src = W1 + ((size_t)s*HID + o)*HID + i;
        float4 v0 = *(const float4*)(src);
        float4 v1 = *(const float4*)(src + 4);
        f16x8 h;
        h[0]=(_Float16)v0.x; h[1]=(_Float16)v0.y; h[2]=(_Float16)v0.z; h[3]=(_Float16)v0.w;
        h[4]=(_Float16)v1.x; h[5]=(_Float16)v1.y; h[6]=(_Float16)v1.z; h[7]=(_Float16)v1.w;
        *(f16x8*)(W1h + (size_t)o*K12V + k) = h;
    } else if (bid < 1344) {               // W2h
        int o = bid - 1024;                 // 0..319
        int k = t * 8;
        int s = k >> 9, i = k & 511;
        f16x8 h = {};
        if (o < OUT_DIM) {
            const float* src = W2 + ((size_t)s*OUT_DIM + o)*HID + i;
            float4 v0 = *(const float4*)(src);
            float4 v1 = *(const float4*)(src + 4);
            h[0]=(_Float16)v0.x; h[1]=(_Float16)v0.y; h[2]=(_Float16)v0.z; h[3]=(_Float16)v0.w;
            h[4]=(_Float16)v1.x; h[5]=(_Float16)v1.y; h[6]=(_Float16)v1.z; h[7]=(_Float16)v1.w;
        }
        *(f16x8*)(W2h + (size_t)o*K12V + k) = h;
    } else {                               // X0h + acoef
        int b = bid - 1344;
        float phase = x[(size_t)b*XROW + IN_DIM];
        float ps = (float)NS * phase;
        float mu = ps - floorf(ps);
        int i1 = ((int)ps) & (NS-1);
        float mu2 = mu*mu, mu3 = mu2*mu;
        float c1 =  1.5f*mu3 - 2.5f*mu2 + 1.0f;        // rel 0
        float c2 = -1.5f*mu3 + 2.0f*mu2 + 0.5f*mu;     // rel 1
        float c3 =  0.5f*mu3 - 0.5f*mu2;               // rel 2
        float c0 = -0.5f*mu3 +      mu2 - 0.5f*mu;     // rel 3
        if (t < 4) {
            int rel = (t - i1) & 3;
            acoef[b*4 + t] = (rel==0)?c1:(rel==1)?c2:(rel==2)?c3:c0;
        }
        for (int k = t; k < K0V; k += 256) {
            int s = k / INP;
            int i = k - s*INP;
            int rel = (s - i1) & 3;
            float sel = (rel==0)?c1:(rel==1)?c2:(rel==2)?c3:c0;
            float v = (i < IN_DIM) ? x[(size_t)b*XROW + i] * sel : 0.f;
            X0h[(size_t)b*K0V + k] = __float2half(v);
        }
    }
}

// ---- MFMA GEMM: BM=32 x BN=64, BK=128, 256 thr (4 waves), acc[2] ----
// R17: A operands go global->VGPR directly (double-buffered aA/aB, depth-2
// prefetch, compiler auto-waitcnt). Only B is staged via gload_lds into a
// 4-slot ring (16KB/slot), depth-3 prefetch, manual counted vmcnt for the
// B-only queue: 8/12 warmup, 16 steady, 12/4 tail. B source pre-swizzled,
// ds_reads swizzled (involution) — unchanged from R12.
template<int LAYER>
__global__ __launch_bounds__(256) void gemm_mfma(
    const __half* __restrict__ A,
    const __half* __restrict__ Bw,
    const float* __restrict__ acoef,
    const float* __restrict__ bias,
    __half* __restrict__ outH,
    float* __restrict__ outF)
{
    constexpr int K  = (LAYER==0) ? K0V : K12V;
    constexpr int NB = (LAYER==2) ? OUT_DIM : HID;
    constexpr int NITER = K / 128;          // 11 / 16 / 16

    __shared__ __align__(16) char lbuf[4][16384];   // B only, 16KB per slot

    const int t    = threadIdx.x;
    const int lane = t & 63;
    const int wid  = t >> 6;
    const int wm   = wid >> 1;
    const int wn   = wid & 1;
    const int m0   = blockIdx.y * 32;
    const int n0   = blockIdx.x * 64;

    // B staging sources (pre-swizzled global chunks), 4 chunks per wave
    const int cS = lane & 15;
    const int r4 = lane >> 4;
    const int rB0 = 4*(wid     ) + r4;
    const int rB1 = 4*(wid +  4) + r4;
    const int rB2 = 4*(wid +  8) + r4;
    const int rB3 = 4*(wid + 12) + r4;
    const __half* bSrc0 = Bw + (size_t)(n0 + rB0)*K + (((cS&8)|((cS&7)^(rB0&7))) * 8);
    const __half* bSrc1 = Bw + (size_t)(n0 + rB1)*K + (((cS&8)|((cS&7)^(rB1&7))) * 8);
    const __half* bSrc2 = Bw + (size_t)(n0 + rB2)*K + (((cS&8)|((cS&7)^(rB2&7))) * 8);
    const __half* bSrc3 = Bw + (size_t)(n0 + rB3)*K + (((cS&8)|((cS&7)^(rB3&7))) * 8);

    // A direct-to-register base: row fixed per lane, 4 lanes/row -> 64B lines
    const __half* aBase = A + (size_t)(m0 + wm*16 + (lane&15))*K + (lane>>4)*8;

    f32x4 acc[2] = {};
    f16x8 aA[4], aB[4];      // static double buffer (rule #20: no runtime idx)

    auto stageB = [&](int it) {
        char* base = lbuf[it & 3];
        const int ko = it * 128;
        gload16(bSrc0 + ko, base + (wid     )*1024);
        gload16(bSrc1 + ko, base + (wid +  4)*1024);
        gload16(bSrc2 + ko, base + (wid +  8)*1024);
        gload16(bSrc3 + ko, base + (wid + 12)*1024);
    };
    auto loadA = [&](int it, f16x8 (&dst)[4]) {
        const __half* p = aBase + it*128;
        #pragma unroll
        for (int kk = 0; kk < 4; ++kk)
            dst[kk] = *(const f16x8*)(p + kk*32);
    };

    // prologue: A loads first so compiler's auto-wait for them never
    // force-drains younger B stages (queue: A0,A1,B0,B1,B2)
    loadA(0, aA);
    if (NITER > 1) loadA(1, aB);
    stageB(0);
    stageB(1);
    stageB(2);

    auto body = [&](int it, f16x8 (&ac)[4]) {
        // manual wait: B(it) complete; leave younger A/B groups in flight
        if (it == 0)                asm volatile("s_waitcnt vmcnt(8)"  ::: "memory");
        else if (it == NITER-1)     asm volatile("s_waitcnt vmcnt(4)"  ::: "memory");
        else if (it == 1)           asm volatile("s_waitcnt vmcnt(12)" ::: "memory");
        else if (it == NITER-2)     asm volatile("s_waitcnt vmcnt(12)" ::: "memory");
        else                        asm volatile("s_waitcnt vmcnt(16)" ::: "memory");
        __builtin_amdgcn_s_barrier();
        __builtin_amdgcn_sched_barrier(0);
        const char* sB = lbuf[it & 3];
        #pragma unroll
        for (int kk = 0; kk < 4; ++kk) {
            const int kb = kk*64 + (lane>>4)*16;
            f16x8 af = ac[kk];
            #pragma unroll
            for (int ni = 0; ni < 2; ++ni) {
                const int oo = wn*32 + ni*16 + (lane&15);
                f16x8 bf = *(const f16x8*)(sB + oo*256 + (kb ^ ((oo&7)<<4)));
                acc[ni] = __builtin_amdgcn_mfma_f32_16x16x32_f16(af, bf, acc[ni], 0, 0, 0);
            }
        }
        if (it + 2 < NITER) loadA(it + 2, ac);   // overwrite after last read
        if (it + 3 < NITER) stageB(it + 3);
    };

    for (int it = 0; it < NITER; ++it) {
        if ((it & 1) == 0) body(it, aA);
        else               body(it, aB);
    }

    // ---- epilogue (proven): D layout col=lane&15, row=(lane>>4)*4+r ----
    #pragma unroll
    for (int r = 0; r < 4; ++r) {
        const int row = m0 + wm*16 + (lane>>4)*4 + r;
        const float c0 = acoef[row*4+0], c1 = acoef[row*4+1],
                    c2 = acoef[row*4+2], c3 = acoef[row*4+3];
        #pragma unroll
        for (int ni = 0; ni < 2; ++ni) {
            const int col = n0 + wn*32 + ni*16 + (lane&15);
            float v = acc[ni][r];
            if (LAYER == 2) {
                if (col < OUT_DIM) {
                    float bi = c0*bias[col] + c1*bias[NB+col]
                             + c2*bias[2*NB+col] + c3*bias[3*NB+col];
                    outF[(size_t)row*OUT_DIM + col] = v + bi;
                }
            } else {
                float bi = c0*bias[col] + c1*bias[NB+col]
                         + c2*bias[2*NB+col] + c3*bias[3*NB+col];
                v += bi;
                v = (v > 0.f) ? v : expm1f(v);
                size_t o = (size_t)row*K12V + col;
                outH[o        ] = __float2half(c0*v);
                outH[o +   HID] = __float2half(c1*v);
                outH[o + 2*HID] = __float2half(c2*v);
                outH[o + 3*HID] = __float2half(c3*v);
            }
        }
    }
}

extern "C" void kernel_launch(void* const* d_in, const int* in_sizes, int n_in,
                              void* d_out, int out_size, void* d_ws, size_t ws_size,
                              hipStream_t stream) {
    const float* x  = (const float*)d_in[0];
    const float* W0 = (const float*)d_in[1];
    const float* W1 = (const float*)d_in[2];
    const float* W2 = (const float*)d_in[3];
    const float* b0 = (const float*)d_in[4];
    const float* b1 = (const float*)d_in[5];
    const float* b2 = (const float*)d_in[6];
    float* out = (float*)d_out;
    float* ws  = (float*)d_ws;

    float*  acoef = ws + OFF_ACOEF;
    __half* X0h   = (__half*)(ws + OFF_X0H);
    __half* W0h   = (__half*)(ws + OFF_W0H);
    __half* W1h   = (__half*)(ws + OFF_W1H);
    __half* W2h   = (__half*)(ws + OFF_W2H);
    __half* H1x   = (__half*)(ws + OFF_H1X);
    __half* H2x   = (__half*)(ws + OFF_H2X);

    prep_all<<<dim3(2368), dim3(256), 0, stream>>>(x, W0, W1, W2, acoef,
                                                   X0h, W0h, W1h, W2h);

    gemm_mfma<0><<<dim3(HID/64, BATCH/32), dim3(256), 0, stream>>>(
        X0h, W0h, acoef, b0, H1x, nullptr);
    gemm_mfma<1><<<dim3(HID/64, BATCH/32), dim3(256), 0, stream>>>(
        H1x, W1h, acoef, b1, H2x, nullptr);
    gemm_mfma<2><<<dim3(320/64, BATCH/32), dim3(256), 0, stream>>>(
        H2x, W2h, acoef, b2, nullptr, out);
}

// Round 18
// 37.605 us; speedup vs baseline: 1.8410x; 1.8410x over previous
//
#include <hip/hip_runtime.h>
#include <hip/hip_fp16.h>
#include <math.h>

typedef _Float16 f16x8 __attribute__((ext_vector_type(8)));
typedef float f32x4 __attribute__((ext_vector_type(4)));

#define NS 4
#define HID 512
#define IN_DIM 342
#define OUT_DIM 311
#define BATCH 1024
#define INP 352            // IN_DIM padded to mult of 32
#define K0V (NS*INP)       // 1408
#define K12V (NS*HID)      // 2048
#define XROW (IN_DIM+1)    // 343

// workspace float offsets (~11.9 MB)
#define OFF_ACOEF 0
#define OFF_X0H   4096
#define OFF_W0H   (OFF_X0H + 720896)
#define OFF_W1H   (OFF_W0H + 360448)
#define OFF_W2H   (OFF_W1H + 524288)
#define OFF_H1X   (OFF_W2H + 327680)
#define OFF_H2X   OFF_X0H      // overlays X0h+part of W0h (dead after L0)

typedef __attribute__((address_space(3))) void lds_t;
typedef __attribute__((address_space(1))) const void gvm_t;
__device__ __forceinline__ void gload16(const void* g, void* l) {
    __builtin_amdgcn_global_load_lds((gvm_t*)g, (lds_t*)l, 16, 0, 0);
}

// ---- fused prep kernel: R12 structure, W0h/X0h branches now f16x8-vectorized ----
__global__ __launch_bounds__(256) void prep_all(
    const float* __restrict__ x,
    const float* __restrict__ W0, const float* __restrict__ W1,
    const float* __restrict__ W2,
    float* __restrict__ acoef,
    __half* __restrict__ X0h, __half* __restrict__ W0h,
    __half* __restrict__ W1h, __half* __restrict__ W2h)
{
    const int bid = blockIdx.x;
    const int t = threadIdx.x;
    if (bid < 512) {                       // W0h row o (vectorized, R18)
        int o = bid;
        if (t < 176) {
            int s = t / 44;                 // 44 chunks of 8 cover 352
            int cm = t - s*44;
            int i = cm * 8;
            f16x8 h = {};
            if (i + 8 <= IN_DIM) {
                const float* src = W0 + ((size_t)s*HID + o)*IN_DIM + i;
                float4 v0 = *(const float4*)(src);
                float4 v1 = *(const float4*)(src + 4);
                h[0]=(_Float16)v0.x; h[1]=(_Float16)v0.y; h[2]=(_Float16)v0.z; h[3]=(_Float16)v0.w;
                h[4]=(_Float16)v1.x; h[5]=(_Float16)v1.y; h[6]=(_Float16)v1.z; h[7]=(_Float16)v1.w;
            } else if (i < IN_DIM) {
                const float* src = W0 + ((size_t)s*HID + o)*IN_DIM + i;
                #pragma unroll
                for (int j=0;j<8;++j) h[j] = (_Float16)((i+j < IN_DIM) ? src[j] : 0.f);
            }
            *(f16x8*)(W0h + (size_t)o*K0V + s*INP + i) = h;
        }
    } else if (bid < 1024) {               // W1h (unchanged)
        int o = bid - 512;
        int k = t * 8;
        int s = k >> 9, i = k & 511;
        const float* src = W1 + ((size_t)s*HID + o)*HID + i;
        float4 v0 = *(const float4*)(src);
        float4 v1 = *(const float4*)(src + 4);
        f16x8 h;
        h[0]=(_Float16)v0.x; h[1]=(_Float16)v0.y; h[2]=(_Float16)v0.z; h[3]=(_Float16)v0.w;
        h[4]=(_Float16)v1.x; h[5]=(_Float16)v1.y; h[6]=(_Float16)v1.z; h[7]=(_Float16)v1.w;
        *(f16x8*)(W1h + (size_t)o*K12V + k) = h;
    } else if (bid < 1344) {               // W2h (unchanged)
        int o = bid - 1024;                 // 0..319
        int k = t * 8;
        int s = k >> 9, i = k & 511;
        f16x8 h = {};
        if (o < OUT_DIM) {
            const float* src = W2 + ((size_t)s*OUT_DIM + o)*HID + i;
            float4 v0 = *(const float4*)(src);
            float4 v1 = *(const float4*)(src + 4);
            h[0]=(_Float16)v0.x; h[1]=(_Float16)v0.y; h[2]=(_Float16)v0.z; h[3]=(_Float16)v0.w;
            h[4]=(_Float16)v1.x; h[5]=(_Float16)v1.y; h[6]=(_Float16)v1.z; h[7]=(_Float16)v1.w;
        }
        *(f16x8*)(W2h + (size_t)o*K12V + k) = h;
    } else {                               // X0h row b + acoef (vectorized, R18)
        int b = bid - 1344;
        float phase = x[(size_t)b*XROW + IN_DIM];
        float ps = (float)NS * phase;
        float mu = ps - floorf(ps);
        int i1 = ((int)ps) & (NS-1);
        float mu2 = mu*mu, mu3 = mu2*mu;
        float r0 =  1.5f*mu3 - 2.5f*mu2 + 1.0f;        // rel 0
        float r1 = -1.5f*mu3 + 2.0f*mu2 + 0.5f*mu;     // rel 1
        float r2 =  0.5f*mu3 - 0.5f*mu2;               // rel 2
        float r3 = -0.5f*mu3 +      mu2 - 0.5f*mu;     // rel 3
        if (t < 4) {
            int rel = (t - i1) & 3;
            acoef[b*4 + t] = (rel==0)?r0:(rel==1)?r1:(rel==2)?r2:r3;
        }
        if (t < 176) {
            int s = t / 44;
            int cm = t - s*44;
            int i = cm * 8;
            int rel = (s - i1) & 3;
            float sc = (rel==0)?r0:(rel==1)?r1:(rel==2)?r2:r3;
            f16x8 h = {};
            if (i + 8 <= IN_DIM) {
                const float* src = x + (size_t)b*XROW + i;
                float4 v0 = *(const float4*)(src);
                float4 v1 = *(const float4*)(src + 4);
                h[0]=(_Float16)(v0.x*sc); h[1]=(_Float16)(v0.y*sc);
                h[2]=(_Float16)(v0.z*sc); h[3]=(_Float16)(v0.w*sc);
                h[4]=(_Float16)(v1.x*sc); h[5]=(_Float16)(v1.y*sc);
                h[6]=(_Float16)(v1.z*sc); h[7]=(_Float16)(v1.w*sc);
            } else if (i < IN_DIM) {
                const float* src = x + (size_t)b*XROW + i;
                #pragma unroll
                for (int j=0;j<8;++j) h[j] = (_Float16)((i+j < IN_DIM) ? src[j]*sc : 0.f);
            }
            *(f16x8*)(X0h + (size_t)b*K0V + s*INP + i) = h;
        }
    }
}

// ---- MFMA GEMM (R12 champion, byte-identical) ----
// BM=32 x BN=64, BK=128, 256 thr (4 waves), acc[2]. gload_lds into a 4-slot
// LDS ring (24KB/slot), depth-3 prefetch, counted vmcnt (12/6/0). LDS dest
// linear; global source pre-swizzled; ds_reads XOR the same bits.
template<int LAYER>
__global__ __launch_bounds__(256) void gemm_mfma(
    const __half* __restrict__ A,
    const __half* __restrict__ Bw,
    const float* __restrict__ acoef,
    const float* __restrict__ bias,
    __half* __restrict__ outH,
    float* __restrict__ outF)
{
    constexpr int K  = (LAYER==0) ? K0V : K12V;
    constexpr int NB = (LAYER==2) ? OUT_DIM : HID;
    constexpr int NITER = K / 128;          // 11 / 16 / 16

    __shared__ __align__(16) char lbuf[4][24576];   // A 8KB | B 16KB per slot

    const int t    = threadIdx.x;
    const int lane = t & 63;
    const int wid  = t >> 6;
    const int wm   = wid >> 1;
    const int wn   = wid & 1;
    const int m0   = blockIdx.y * 32;
    const int n0   = blockIdx.x * 64;

    // per-lane staging source addresses (pre-swizzled global chunks)
    const int cS = lane & 15;               // lds 16B-chunk within row
    const int r4 = lane >> 4;               // row within 1KB gload chunk
    const int rA0 = 4*(wid    ) + r4;
    const int rA1 = 4*(wid + 4) + r4;
    const __half* aSrc0 = A + (size_t)(m0 + rA0)*K + (((cS&8)|((cS&7)^(rA0&7))) * 8);
    const __half* aSrc1 = A + (size_t)(m0 + rA1)*K + (((cS&8)|((cS&7)^(rA1&7))) * 8);
    const int rB0 = 4*(wid     ) + r4;
    const int rB1 = 4*(wid +  4) + r4;
    const int rB2 = 4*(wid +  8) + r4;
    const int rB3 = 4*(wid + 12) + r4;
    const __half* bSrc0 = Bw + (size_t)(n0 + rB0)*K + (((cS&8)|((cS&7)^(rB0&7))) * 8);
    const __half* bSrc1 = Bw + (size_t)(n0 + rB1)*K + (((cS&8)|((cS&7)^(rB1&7))) * 8);
    const __half* bSrc2 = Bw + (size_t)(n0 + rB2)*K + (((cS&8)|((cS&7)^(rB2&7))) * 8);
    const __half* bSrc3 = Bw + (size_t)(n0 + rB3)*K + (((cS&8)|((cS&7)^(rB3&7))) * 8);

    f32x4 acc[2] = {};

    auto stage = [&](int it) {
        char* base = lbuf[it & 3];
        const int ko = it * 128;
        gload16(aSrc0 + ko, base + (wid    )*1024);
        gload16(aSrc1 + ko, base + (wid + 4)*1024);
        gload16(bSrc0 + ko, base + 8192 + (wid     )*1024);
        gload16(bSrc1 + ko, base + 8192 + (wid +  4)*1024);
        gload16(bSrc2 + ko, base + 8192 + (wid +  8)*1024);
        gload16(bSrc3 + ko, base + 8192 + (wid + 12)*1024);
    };

    stage(0);
    stage(1);
    stage(2);

    for (int it = 0; it < NITER; ++it) {
        if (it + 2 < NITER)      asm volatile("s_waitcnt vmcnt(12)" ::: "memory");
        else if (it + 1 < NITER) asm volatile("s_waitcnt vmcnt(6)"  ::: "memory");
        else                     asm volatile("s_waitcnt vmcnt(0)"  ::: "memory");
        __builtin_amdgcn_s_barrier();
        __builtin_amdgcn_sched_barrier(0);
        if (it + 3 < NITER) stage(it + 3);
        const char* sA = lbuf[it & 3];
        const char* sB = sA + 8192;
        #pragma unroll
        for (int kk = 0; kk < 4; ++kk) {
            const int kb = kk*64 + (lane>>4)*16;
            const int rr = wm*16 + (lane&15);
            f16x8 af = *(const f16x8*)(sA + rr*256 + (kb ^ ((rr&7)<<4)));
            #pragma unroll
            for (int ni = 0; ni < 2; ++ni) {
                const int oo = wn*32 + ni*16 + (lane&15);
                f16x8 bf = *(const f16x8*)(sB + oo*256 + (kb ^ ((oo&7)<<4)));
                acc[ni] = __builtin_amdgcn_mfma_f32_16x16x32_f16(af, bf, acc[ni], 0, 0, 0);
            }
        }
    }

    // ---- epilogue (proven): D layout col=lane&15, row=(lane>>4)*4+r ----
    #pragma unroll
    for (int r = 0; r < 4; ++r) {
        const int row = m0 + wm*16 + (lane>>4)*4 + r;
        const float c0 = acoef[row*4+0], c1 = acoef[row*4+1],
                    c2 = acoef[row*4+2], c3 = acoef[row*4+3];
        #pragma unroll
        for (int ni = 0; ni < 2; ++ni) {
            const int col = n0 + wn*32 + ni*16 + (lane&15);
            float v = acc[ni][r];
            if (LAYER == 2) {
                if (col < OUT_DIM) {
                    float bi = c0*bias[col] + c1*bias[NB+col]
                             + c2*bias[2*NB+col] + c3*bias[3*NB+col];
                    outF[(size_t)row*OUT_DIM + col] = v + bi;
                }
            } else {
                float bi = c0*bias[col] + c1*bias[NB+col]
                         + c2*bias[2*NB+col] + c3*bias[3*NB+col];
                v += bi;
                v = (v > 0.f) ? v : expm1f(v);
                size_t o = (size_t)row*K12V + col;
                outH[o        ] = __float2half(c0*v);
                outH[o +   HID] = __float2half(c1*v);
                outH[o + 2*HID] = __float2half(c2*v);
                outH[o + 3*HID] = __float2half(c3*v);
            }
        }
    }
}

extern "C" void kernel_launch(void* const* d_in, const int* in_sizes, int n_in,
                              void* d_out, int out_size, void* d_ws, size_t ws_size,
                              hipStream_t stream) {
    const float* x  = (const float*)d_in[0];
    const float* W0 = (const float*)d_in[1];
    const float* W1 = (const float*)d_in[2];
    const float* W2 = (const float*)d_in[3];
    const float* b0 = (const float*)d_in[4];
    const float* b1 = (const float*)d_in[5];
    const float* b2 = (const float*)d_in[6];
    float* out = (float*)d_out;
    float* ws  = (float*)d_ws;

    float*  acoef = ws + OFF_ACOEF;
    __half* X0h   = (__half*)(ws + OFF_X0H);
    __half* W0h   = (__half*)(ws + OFF_W0H);
    __half* W1h   = (__half*)(ws + OFF_W1H);
    __half* W2h   = (__half*)(ws + OFF_W2H);
    __half* H1x   = (__half*)(ws + OFF_H1X);
    __half* H2x   = (__half*)(ws + OFF_H2X);

    prep_all<<<dim3(2368), dim3(256), 0, stream>>>(x, W0, W1, W2, acoef,
                                                   X0h, W0h, W1h, W2h);

    gemm_mfma<0><<<dim3(HID/64, BATCH/32), dim3(256), 0, stream>>>(
        X0h, W0h, acoef, b0, H1x, nullptr);
    gemm_mfma<1><<<dim3(HID/64, BATCH/32), dim3(256), 0, stream>>>(
        H1x, W1h, acoef, b1, H2x, nullptr);
    gemm_mfma<2><<<dim3(320/64, BATCH/32), dim3(256), 0, stream>>>(
        H2x, W2h, acoef, b2, nullptr, out);
}